// Round 1
// baseline (407.272 us; speedup 1.0000x reference)
//
#include <hip/hip_runtime.h>

#define U 256       // unknown node count
#define NN 1024     // total nodes
#define NROWS 32768 // B*T rows
#define LCAP 32     // capacity of "less" (earlier-unknown-neighbor) list per node

typedef __bf16 bf16_t;
typedef __bf16 bf16x4 __attribute__((ext_vector_type(4)));
typedef __bf16 bf16x8 __attribute__((ext_vector_type(8)));
typedef float f32x4 __attribute__((ext_vector_type(4)));

// ---------------------------------------------------------------------------
// K0: per unknown node k: deg, 1/deg, coef[k] = (#unknown nbrs with pos>=k,
// incl self)*mask/deg, and list of unknown-neighbor positions j<k.
// Also builds uflag[n] = 1 if node n is unknown.
// ---------------------------------------------------------------------------
__global__ __launch_bounds__(256) void k_struct(const float* __restrict__ A,
    const int* __restrict__ unknown, const float* __restrict__ maskp,
    float* __restrict__ invDeg, float* __restrict__ coef,
    int* __restrict__ lessCnt, unsigned char* __restrict__ lessIdx,
    int* __restrict__ uflag)
{
    __shared__ int sunk[U];
    __shared__ float sdeg;
    __shared__ int scnt, sge;
    int t = threadIdx.x, k = blockIdx.x;
    sunk[t] = unknown[t];
    if (t == 0) { sdeg = 0.f; scnt = 0; sge = 0; }
    __syncthreads();
    int uk = sunk[k];
    float dsum = 0.f;
    for (int i = 0; i < NN / 256; ++i) {
        int n = t + 256 * i;
        float a = A[(size_t)uk * NN + n];
        if (a != 0.f) {
            dsum += a;
            // binary search n in sorted unknown[]
            int lo = 0, hi = U;
            while (lo < hi) { int mid = (lo + hi) >> 1; if (sunk[mid] < n) lo = mid + 1; else hi = mid; }
            if (lo < U && sunk[lo] == n) {
                if (lo < k) {
                    int id = atomicAdd(&scnt, 1);
                    if (id < LCAP) lessIdx[k * LCAP + id] = (unsigned char)lo;
                } else {
                    atomicAdd(&sge, 1);
                }
            }
        }
    }
    atomicAdd(&sdeg, dsum);
    __syncthreads();
    if (t == 0) {
        float inv = 1.f / sdeg;
        invDeg[k] = inv;
        coef[k] = (float)sge * maskp[0] * inv;
        lessCnt[k] = min(scnt, LCAP);
    }
    if (k == 0) {
        for (int i = 0; i < NN / 256; ++i) uflag[t + 256 * i] = 0;
        __syncthreads();
        uflag[sunk[t]] = 1;
    }
}

// ---------------------------------------------------------------------------
// K1: forward substitution M = (I - L)^-1, M[k][c] = delta(k,c)
//     + invDeg[k]*sum_{j in less(k)} M[j][c].  8 blocks x 32 columns.
//     Stores M transposed: MT[c*U + k] = M[k][c].
// ---------------------------------------------------------------------------
__global__ __launch_bounds__(32) void k_mbuild(const int* __restrict__ lessCnt,
    const unsigned char* __restrict__ lessIdx, const float* __restrict__ invDeg,
    float* __restrict__ MT)
{
    __shared__ float Ms[U * 32];           // 32 KiB: M slice [k][c-local]
    __shared__ unsigned char sIdx[U * LCAP]; // 8 KiB
    __shared__ unsigned char sCnt[U];
    __shared__ float sInv[U];
    int l = threadIdx.x;                   // 0..31
    int c = blockIdx.x * 32 + l;
    for (int i = l; i < U * LCAP / 4; i += 32) ((int*)sIdx)[i] = ((const int*)lessIdx)[i];
    for (int i = l; i < U; i += 32) { sCnt[i] = (unsigned char)lessCnt[i]; sInv[i] = invDeg[i]; }
    __syncthreads();
    for (int k = 0; k < U; ++k) {
        int cnt = sCnt[k];
        float s = 0.f;
        for (int i = 0; i < cnt; ++i) {
            int j = sIdx[k * LCAP + i];
            s += Ms[j * 32 + l];
        }
        float m = (c == k ? 1.f : 0.f) + sInv[k] * s;
        Ms[k * 32 + l] = m;
        MT[(size_t)c * U + k] = m;
        __syncthreads();
    }
}

// ---------------------------------------------------------------------------
// K2: W[u][d] = sum_{c<=u} M[u][c] * invDeg[c] * A[unknown[c]][d] for known d,
//     0 for unknown d (so the GEMM never uses x at unknown columns).
//     Exploits column sparsity of A (~8 nonzeros per column among 256 rows).
//     Block d==NN computes bvec[u] = sum_c M[u][c]*coef[c].
// ---------------------------------------------------------------------------
__global__ __launch_bounds__(256) void k_wbuild(const float* __restrict__ A,
    const int* __restrict__ unknown, const float* __restrict__ invDeg,
    const float* __restrict__ coef, const int* __restrict__ uflag,
    const float* __restrict__ MT, bf16_t* __restrict__ Wb, float* __restrict__ bvec)
{
    int t = threadIdx.x, d = blockIdx.x;
    if (d == NN) {
        float s = 0.f;
        for (int c = 0; c <= t; ++c) s += MT[(size_t)c * U + t] * coef[c];
        bvec[t] = s;
        return;
    }
    if (uflag[d]) { Wb[(size_t)t * NN + d] = (bf16_t)0.f; return; }  // block-uniform
    __shared__ int nnz;
    __shared__ int cs[64];
    __shared__ float vsv[64];
    if (t == 0) nnz = 0;
    __syncthreads();
    float a = A[(size_t)unknown[t] * NN + d];
    if (a != 0.f) {
        int id = atomicAdd(&nnz, 1);
        if (id < 64) { cs[id] = t; vsv[id] = a * invDeg[t]; }
    }
    __syncthreads();
    int n = min(nnz, 64);
    float s = 0.f;
    for (int i = 0; i < n; ++i) {
        int c = cs[i];
        if (c <= t) s += MT[(size_t)c * U + t] * vsv[i];  // MT read coalesced over t
    }
    Wb[(size_t)t * NN + d] = (bf16_t)s;
}

// ---------------------------------------------------------------------------
// K3: fused stream copy x->out (fp32 exact) + GEMM out[:,unknown] = x*W^T + b
//     64 rows/block, full U=256 output cols, K=1024 in BK=64 chunks.
//     bf16 MFMA 16x16x32; wave w covers u-tiles 4w..4w+3, all 4 row-tiles.
// ---------------------------------------------------------------------------
#define RT 64
#define BK 64
#define LDX 72   // 64 + 8 bf16 pad: keeps 16B alignment, 2-way-max LDS banks

__global__ __launch_bounds__(256) void k_main(const float* __restrict__ x,
    const int* __restrict__ unknown, const bf16_t* __restrict__ Wb,
    const float* __restrict__ bvec, float* __restrict__ out)
{
    __shared__ __align__(16) bf16_t Xl[RT * LDX];   // 9216 B
    __shared__ __align__(16) bf16_t Vl[U * LDX];    // 36864 B
    __shared__ int sunk[U];
    __shared__ float sb[U];
    int t = threadIdx.x;
    int w = t >> 6, l = t & 63;
    size_t row0 = (size_t)blockIdx.x * RT;
    sunk[t] = unknown[t];
    sb[t] = bvec[t];
    f32x4 acc[4][4] = {};
    int rs = t >> 2;            // staging row 0..63
    int c4 = (t & 3) * 4;
    int uv = t >> 3;            // staging u 0..31
    int du = (t & 7) * 8;
    int m = l & 15, q = l >> 4;
    for (int db = 0; db < NN; db += BK) {
        __syncthreads();   // LDS reuse guard (also covers sunk/sb on first iter)
        // --- stage X chunk [64r x 64d]: global fp32 -> out copy + bf16 -> LDS
        const float* xp = x + (row0 + rs) * NN + db;
        float* op = out + (row0 + rs) * NN + db;
        #pragma unroll
        for (int i = 0; i < 4; ++i) {
            int dl = c4 + i * 16;
            float4 v = *(const float4*)(xp + dl);
            *(float4*)(op + dl) = v;
            bf16x4 hv = { (bf16_t)v.x, (bf16_t)v.y, (bf16_t)v.z, (bf16_t)v.w };
            *(bf16x4*)(&Xl[rs * LDX + dl]) = hv;
        }
        // --- stage V chunk [256u x 64d] bf16 from Wb ([u][d] row-major)
        #pragma unroll
        for (int i = 0; i < 8; ++i) {
            int u = uv + 32 * i;
            *(bf16x8*)(&Vl[u * LDX + du]) = *(const bf16x8*)(Wb + (size_t)u * NN + db + du);
        }
        __syncthreads();
        // --- MFMA: A[m=l&15][k=q*8+j], B[k=q*8+j][n=l&15] (Vl is [u][d])
        #pragma unroll
        for (int s = 0; s < 2; ++s) {
            bf16x8 af[4];
            #pragma unroll
            for (int R = 0; R < 4; ++R)
                af[R] = *(bf16x8*)(&Xl[(R * 16 + m) * LDX + s * 32 + q * 8]);
            #pragma unroll
            for (int T = 0; T < 4; ++T) {
                bf16x8 bfr = *(bf16x8*)(&Vl[((w * 4 + T) * 16 + m) * LDX + s * 32 + q * 8]);
                #pragma unroll
                for (int R = 0; R < 4; ++R)
                    acc[R][T] = __builtin_amdgcn_mfma_f32_16x16x32_bf16(af[R], bfr, acc[R][T], 0, 0, 0);
            }
        }
    }
    __syncthreads();  // copy stores drained (compiler emits vmcnt(0) before barrier)
    // --- epilogue: C/D layout row=(l>>4)*4+i, col=l&15; scatter into unknown cols
    #pragma unroll
    for (int R = 0; R < 4; ++R) {
        #pragma unroll
        for (int T = 0; T < 4; ++T) {
            int u = (w * 4 + T) * 16 + m;
            int col = sunk[u];
            float bb = sb[u];
            #pragma unroll
            for (int i = 0; i < 4; ++i) {
                size_t r = row0 + R * 16 + q * 4 + i;
                out[r * NN + col] = acc[R][T][i] + bb;
            }
        }
    }
}

// ---------------------------------------------------------------------------
extern "C" void kernel_launch(void* const* d_in, const int* in_sizes, int n_in,
                              void* d_out, int out_size, void* d_ws, size_t ws_size,
                              hipStream_t stream)
{
    const float* x       = (const float*)d_in[0];
    const float* A       = (const float*)d_in[1];
    const int*   unknown = (const int*)d_in[2];
    const float* maskp   = (const float*)d_in[3];
    float* out = (float*)d_out;

    char* ws = (char*)d_ws;
    float*         MT      = (float*)(ws + 0);        // 256*256 f32 = 262144 B
    bf16_t*        Wb      = (bf16_t*)(ws + 262144);  // 256*1024 bf16 = 524288 B
    float*         invDeg  = (float*)(ws + 786432);   // 1 KiB
    float*         coef    = (float*)(ws + 787456);   // 1 KiB
    float*         bvec    = (float*)(ws + 788480);   // 1 KiB
    int*           lessCnt = (int*)(ws + 789504);     // 1 KiB
    unsigned char* lessIdx = (unsigned char*)(ws + 790528); // 8 KiB
    int*           uflag   = (int*)(ws + 798720);     // 4 KiB

    hipLaunchKernelGGL(k_struct, dim3(U), dim3(256), 0, stream,
                       A, unknown, maskp, invDeg, coef, lessCnt, lessIdx, uflag);
    hipLaunchKernelGGL(k_mbuild, dim3(8), dim3(32), 0, stream,
                       lessCnt, lessIdx, invDeg, MT);
    hipLaunchKernelGGL(k_wbuild, dim3(NN + 1), dim3(256), 0, stream,
                       A, unknown, invDeg, coef, uflag, MT, Wb, bvec);
    hipLaunchKernelGGL(k_main, dim3(NROWS / RT), dim3(256), 0, stream,
                       x, unknown, Wb, bvec, out);
}

// Round 2
// 348.349 us; speedup vs baseline: 1.1691x; 1.1691x over previous
//
#include <hip/hip_runtime.h>

#define U 256       // unknown node count
#define NN 1024     // total nodes
#define NROWS 32768 // B*T rows
#define LCAP 32     // capacity of "less" (earlier-unknown-neighbor) list per node
#define DUMMY 256   // padded index -> zero row of Ms

typedef __bf16 bf16_t;
typedef __bf16 bf16x4 __attribute__((ext_vector_type(4)));
typedef __bf16 bf16x8 __attribute__((ext_vector_type(8)));
typedef float f32x4 __attribute__((ext_vector_type(4)));
typedef unsigned short u16;
typedef unsigned short u16x8 __attribute__((ext_vector_type(8)));
typedef short s16x4 __attribute__((ext_vector_type(4)));

// ---------------------------------------------------------------------------
// K0: per unknown node k (one block each): deg, 1/deg, coef, less-list
// (ushort, padded with DUMMY). Block 0 also builds uflag + pmap.
// ---------------------------------------------------------------------------
__global__ __launch_bounds__(256) void k_struct(const float* __restrict__ A,
    const int* __restrict__ unknown, const float* __restrict__ maskp,
    float* __restrict__ invDeg, float* __restrict__ coef,
    int* __restrict__ lessCnt, u16* __restrict__ lessIdx,
    int* __restrict__ uflag, short* __restrict__ pmap)
{
    __shared__ int sunk[U];
    __shared__ float sdeg;
    __shared__ int scnt, sge;
    int t = threadIdx.x, k = blockIdx.x;
    sunk[t] = unknown[t];
    if (t == 0) { sdeg = 0.f; scnt = 0; sge = 0; }
    __syncthreads();
    int uk = sunk[k];
    float dsum = 0.f;
    for (int i = 0; i < NN / 256; ++i) {
        int n = t + 256 * i;
        float a = A[(size_t)uk * NN + n];
        if (a != 0.f) {
            dsum += a;
            int lo = 0, hi = U;
            while (lo < hi) { int mid = (lo + hi) >> 1; if (sunk[mid] < n) lo = mid + 1; else hi = mid; }
            if (lo < U && sunk[lo] == n) {
                if (lo < k) {
                    int id = atomicAdd(&scnt, 1);
                    if (id < LCAP) lessIdx[k * LCAP + id] = (u16)lo;
                } else {
                    atomicAdd(&sge, 1);
                }
            }
        }
    }
    atomicAdd(&sdeg, dsum);
    __syncthreads();
    int c0 = min(scnt, LCAP);
    if (t >= c0 && t < LCAP) lessIdx[k * LCAP + t] = DUMMY;   // pad
    if (t == 0) {
        float inv = 1.f / sdeg;
        invDeg[k] = inv;
        coef[k] = (float)sge * maskp[0] * inv;
        lessCnt[k] = c0;
    }
    if (k == 0) {
        for (int i = 0; i < NN / 256; ++i) { uflag[t + 256 * i] = 0; pmap[t + 256 * i] = -1; }
        __syncthreads();
        uflag[sunk[t]] = 1;
        pmap[sunk[t]] = (short)t;
    }
}

// ---------------------------------------------------------------------------
// K0b: topological levels of the unknown-DAG (Jacobi relaxation to fixpoint,
// correct for any depth) + counting sort -> order[], levelStart[], nLev.
// ---------------------------------------------------------------------------
__global__ __launch_bounds__(256) void k_levels(const int* __restrict__ lessCnt,
    const u16* __restrict__ lessIdx, int* __restrict__ order,
    int* __restrict__ levelStart, int* __restrict__ nLevOut)
{
    __shared__ u16 sIdx[U * LCAP];
    __shared__ int slvl[U];
    __shared__ int sc[U];
    __shared__ int hist[U];
    __shared__ int changed;
    int t = threadIdx.x;
    for (int i = t; i < U * LCAP / 2; i += 256) ((unsigned int*)sIdx)[i] = ((const unsigned int*)lessIdx)[i];
    sc[t] = lessCnt[t];
    slvl[t] = 0; hist[t] = 0;
    __syncthreads();
    for (int iter = 0; iter < U; ++iter) {
        if (t == 0) changed = 0;
        __syncthreads();
        int c = sc[t], nl = 0;
        for (int i = 0; i < c; ++i) nl = max(nl, slvl[sIdx[t * LCAP + i]] + 1);
        if (nl > slvl[t]) { slvl[t] = nl; changed = 1; }
        __syncthreads();
        if (!changed) break;   // uniform
    }
    int L = slvl[t];
    atomicAdd(&hist[L], 1);
    __syncthreads();
    if (t == 0) {
        int acc = 0, lastl = 0;
        for (int l = 0; l < U; ++l) {
            int h = hist[l];
            hist[l] = acc;          // hist becomes start offset
            acc += h;
            if (h > 0) lastl = l;
        }
        nLevOut[0] = lastl + 1;
    }
    __syncthreads();
    levelStart[t] = hist[t];        // save starts to global BEFORE scatter clobbers
    if (t == 0) levelStart[U] = U;
    __syncthreads();
    int pos = atomicAdd(&hist[L], 1);
    order[pos] = t;
}

// ---------------------------------------------------------------------------
// K1: M = (I - Ltilde)^-1 by LEVEL-PARALLEL forward substitution.
// 8 blocks x 32 cols; 256 thr = 8 node-slots x 32 cols. Batched (8-wide,
// dummy-padded) LDS loads -> no per-neighbor waitcnt chain.
// Stores MT[c*U + k] = M[k][c] (exactly 0 above diagonal).
// ---------------------------------------------------------------------------
__global__ __launch_bounds__(256) void k_mbuild(const int* __restrict__ lessCnt,
    const u16* __restrict__ lessIdx, const float* __restrict__ invDeg,
    const int* __restrict__ order, const int* __restrict__ levelStart,
    const int* __restrict__ nLevp, float* __restrict__ MT)
{
    __shared__ float Ms[(U + 1) * 32];    // row U = zeros (dummy target)
    __shared__ u16 sIdx[U * LCAP];
    __shared__ float sInv[U];
    __shared__ u16 sOrd[U];
    __shared__ unsigned char sCnt[U];
    __shared__ int sLs[U + 1];
    int t = threadIdx.x;
    int g = t >> 5, c = t & 31;
    int col = blockIdx.x * 32 + c;
    for (int i = t; i < U * LCAP / 2; i += 256) ((unsigned int*)sIdx)[i] = ((const unsigned int*)lessIdx)[i];
    sInv[t] = invDeg[t];
    sOrd[t] = (u16)order[t];
    sCnt[t] = (unsigned char)lessCnt[t];
    sLs[t] = levelStart[t];
    if (t == 0) sLs[U] = levelStart[U];
    if (t < 32) Ms[U * 32 + t] = 0.f;
    int nLev = nLevp[0];
    __syncthreads();
    for (int lev = 0; lev < nLev; ++lev) {
        int s = sLs[lev], e = sLs[lev + 1];
        for (int base = s + g; base < e; base += 8) {
            int k = sOrd[base];
            int cnt = sCnt[k];
            const u16* ip = &sIdx[k * LCAP];
            float sum = 0.f;
            for (int b = 0; b < cnt; b += 8) {
                u16x8 jv = *(const u16x8*)(ip + b);   // one ds_read_b128
                float v0 = Ms[jv[0] * 32 + c];
                float v1 = Ms[jv[1] * 32 + c];
                float v2 = Ms[jv[2] * 32 + c];
                float v3 = Ms[jv[3] * 32 + c];
                float v4 = Ms[jv[4] * 32 + c];
                float v5 = Ms[jv[5] * 32 + c];
                float v6 = Ms[jv[6] * 32 + c];
                float v7 = Ms[jv[7] * 32 + c];
                sum += ((v0 + v1) + (v2 + v3)) + ((v4 + v5) + (v6 + v7));
            }
            float m = (k == col ? 1.f : 0.f) + sInv[k] * sum;
            Ms[k * 32 + c] = m;
            MT[(size_t)col * U + k] = m;
        }
        __syncthreads();   // level boundary
    }
}

// ---------------------------------------------------------------------------
// K2: W[u][d] (bf16) and bvec. Upper-triangle MT entries are exact zeros so
// no c<=t predicates; bvec loop is fixed-bound -> pipelined loads.
// ---------------------------------------------------------------------------
__global__ __launch_bounds__(256) void k_wbuild(const float* __restrict__ A,
    const int* __restrict__ unknown, const float* __restrict__ invDeg,
    const float* __restrict__ coef, const int* __restrict__ uflag,
    const float* __restrict__ MT, bf16_t* __restrict__ Wb, float* __restrict__ bvec)
{
    int t = threadIdx.x, d = blockIdx.x;
    if (d == NN) {
        __shared__ float scf[U];
        scf[t] = coef[t];
        __syncthreads();
        float s = 0.f;
        #pragma unroll 8
        for (int c = 0; c < U; ++c) s += MT[(size_t)c * U + t] * scf[c];
        bvec[t] = s;
        return;
    }
    if (uflag[d]) { Wb[(size_t)t * NN + d] = (bf16_t)0.f; return; }  // block-uniform
    __shared__ int nnz;
    __shared__ int cs[64];
    __shared__ float vsv[64];
    if (t == 0) nnz = 0;
    __syncthreads();
    float a = A[(size_t)unknown[t] * NN + d];
    if (a != 0.f) {
        int id = atomicAdd(&nnz, 1);
        if (id < 64) { cs[id] = t; vsv[id] = a * invDeg[t]; }
    }
    __syncthreads();
    int n = min(nnz, 64);
    float s = 0.f;
    for (int i = 0; i < n; ++i)
        s += MT[(size_t)cs[i] * U + t] * vsv[i];   // coalesced over t; zero above diag
    Wb[(size_t)t * NN + d] = (bf16_t)s;
}

// ---------------------------------------------------------------------------
// K3: GEMM out[:,unknown] = x*W^T + b with NO writes in the K-loop; epilogue
// stages acc in LDS (reusing the staging region), re-reads x (L3-warm) and
// writes every out line exactly once, fully merged + coalesced.
// RT=32 rows/block -> grid 1024 (3 blocks/CU LDS-resident).
// ---------------------------------------------------------------------------
#define RT 32
#define BK 64
#define LDX 72      // 64 + 8 bf16 pad: 2-way-max LDS banks
#define URS 257     // Ures row stride (f32)

__global__ __launch_bounds__(256) void k_main(const float* __restrict__ x,
    const short* __restrict__ pmap, const bf16_t* __restrict__ Wb,
    const float* __restrict__ bvec, float* __restrict__ out)
{
    __shared__ __align__(16) char smem[41472];  // max(Xl 4608 + Vl 36864, Ures 32896)
    __shared__ float sb[U];
    __shared__ short spm[NN];
    bf16_t* Xl = (bf16_t*)smem;
    bf16_t* Vl = (bf16_t*)(smem + 4608);
    float* Ures = (float*)smem;
    int t = threadIdx.x;
    int w = t >> 6, l = t & 63;
    int m = l & 15, q = l >> 4;
    size_t row0 = (size_t)blockIdx.x * RT;
    sb[t] = bvec[t];
    #pragma unroll
    for (int j = 0; j < 4; ++j) spm[t + 256 * j] = pmap[t + 256 * j];
    f32x4 acc[2][4] = {};
    int uv = t >> 3, du = (t & 7) * 8;
    for (int db = 0; db < NN; db += BK) {
        __syncthreads();   // LDS reuse guard (covers sb/spm on first iter)
        // stage X chunk [32r x 64d] fp32 -> bf16 LDS (no out write here)
        #pragma unroll
        for (int ii = 0; ii < 2; ++ii) {
            int flat = t + ii * 256;
            int r = flat >> 4, c4 = (flat & 15) * 4;
            float4 v = *(const float4*)(x + (row0 + r) * NN + db + c4);
            bf16x4 hv = { (bf16_t)v.x, (bf16_t)v.y, (bf16_t)v.z, (bf16_t)v.w };
            *(bf16x4*)(&Xl[r * LDX + c4]) = hv;
        }
        // stage V chunk [256u x 64d] bf16
        #pragma unroll
        for (int i = 0; i < 8; ++i) {
            int u = uv + 32 * i;
            *(bf16x8*)(&Vl[u * LDX + du]) = *(const bf16x8*)(Wb + (size_t)u * NN + db + du);
        }
        __syncthreads();
        #pragma unroll
        for (int s = 0; s < 2; ++s) {
            bf16x8 af[2];
            #pragma unroll
            for (int R = 0; R < 2; ++R)
                af[R] = *(bf16x8*)(&Xl[(R * 16 + m) * LDX + s * 32 + q * 8]);
            #pragma unroll
            for (int T = 0; T < 4; ++T) {
                bf16x8 bfr = *(bf16x8*)(&Vl[((w * 4 + T) * 16 + m) * LDX + s * 32 + q * 8]);
                #pragma unroll
                for (int R = 0; R < 2; ++R)
                    acc[R][T] = __builtin_amdgcn_mfma_f32_16x16x32_bf16(af[R], bfr, acc[R][T], 0, 0, 0);
            }
        }
    }
    __syncthreads();   // all Vl/Xl reads done before Ures overwrite
    // stage acc (+bias) into Ures[r][u] f32; C/D layout row=q*4+i, col=m
    #pragma unroll
    for (int R = 0; R < 2; ++R) {
        #pragma unroll
        for (int T = 0; T < 4; ++T) {
            int u = (w * 4 + T) * 16 + m;
            float bb = sb[u];
            #pragma unroll
            for (int i = 0; i < 4; ++i)
                Ures[(R * 16 + q * 4 + i) * URS + u] = acc[R][T][i] + bb;
        }
    }
    __syncthreads();
    // merged single-pass write: re-read x (L3-warm), substitute unknown cols
    s16x4 pm = *(const s16x4*)(&spm[t * 4]);
    #pragma unroll 4
    for (int i = 0; i < RT; ++i) {
        float4 v = *(const float4*)(x + (row0 + i) * NN + t * 4);
        if (pm[0] >= 0) v.x = Ures[i * URS + pm[0]];
        if (pm[1] >= 0) v.y = Ures[i * URS + pm[1]];
        if (pm[2] >= 0) v.z = Ures[i * URS + pm[2]];
        if (pm[3] >= 0) v.w = Ures[i * URS + pm[3]];
        *(float4*)(out + (row0 + i) * NN + t * 4) = v;
    }
}

// ---------------------------------------------------------------------------
extern "C" void kernel_launch(void* const* d_in, const int* in_sizes, int n_in,
                              void* d_out, int out_size, void* d_ws, size_t ws_size,
                              hipStream_t stream)
{
    const float* x       = (const float*)d_in[0];
    const float* A       = (const float*)d_in[1];
    const int*   unknown = (const int*)d_in[2];
    const float* maskp   = (const float*)d_in[3];
    float* out = (float*)d_out;

    char* ws = (char*)d_ws;
    float*  MT        = (float*)(ws + 0);        // 262144 B
    bf16_t* Wb        = (bf16_t*)(ws + 262144);  // 524288 B
    float*  invDeg    = (float*)(ws + 786432);
    float*  coef      = (float*)(ws + 787456);
    float*  bvec      = (float*)(ws + 788480);
    int*    lessCnt   = (int*)(ws + 789504);
    u16*    lessIdx   = (u16*)(ws + 790528);     // 16384 B
    int*    uflag     = (int*)(ws + 806912);     // 4096 B
    short*  pmap      = (short*)(ws + 811008);   // 2048 B
    int*    order     = (int*)(ws + 813056);     // 1024 B
    int*    levelStart= (int*)(ws + 814080);     // 1040 B
    int*    nLev      = (int*)(ws + 815120);     // 4 B

    hipLaunchKernelGGL(k_struct, dim3(U), dim3(256), 0, stream,
                       A, unknown, maskp, invDeg, coef, lessCnt, lessIdx, uflag, pmap);
    hipLaunchKernelGGL(k_levels, dim3(1), dim3(256), 0, stream,
                       lessCnt, lessIdx, order, levelStart, nLev);
    hipLaunchKernelGGL(k_mbuild, dim3(8), dim3(256), 0, stream,
                       lessCnt, lessIdx, invDeg, order, levelStart, nLev, MT);
    hipLaunchKernelGGL(k_wbuild, dim3(NN + 1), dim3(256), 0, stream,
                       A, unknown, invDeg, coef, uflag, MT, Wb, bvec);
    hipLaunchKernelGGL(k_main, dim3(NROWS / RT), dim3(256), 0, stream,
                       x, pmap, Wb, bvec, out);
}